// Round 17
// baseline (264.941 us; speedup 1.0000x reference)
//
#include <hip/hip_runtime.h>

#define Sn 1024
#define Dn 64
#define PH_LD 1032   // ushorts/row: 516 dw ≡ 4 (mod 32) -> conflict-min (verified r10)
#define K_LD 72
#define V_LD 72

typedef short v8s __attribute__((ext_vector_type(8)));
typedef unsigned short v8u __attribute__((ext_vector_type(8)));
typedef _Float16 v8h __attribute__((ext_vector_type(8)));
typedef float v4f __attribute__((ext_vector_type(4)));
typedef int   v4i __attribute__((ext_vector_type(4)));

#define LGKM0()  asm volatile("s_waitcnt lgkmcnt(0)" ::: "memory")
#define SBAR()   do { asm volatile("" ::: "memory"); __builtin_amdgcn_s_barrier(); \
                      __builtin_amdgcn_sched_barrier(0); } while (0)

__device__ __forceinline__ unsigned short f2bf(float x) {
    union { float f; unsigned u; } v; v.f = x;
    return (unsigned short)((v.u + 0x7FFFu + ((v.u >> 16) & 1u)) >> 16);
}
__device__ __forceinline__ float bf2f(unsigned short h) {
    union { float f; unsigned u; } v; v.u = ((unsigned)h) << 16;
    return v.f;
}
__device__ __forceinline__ void split2(float x, unsigned short& h, unsigned short& l) {
    unsigned short hs = f2bf(x);
    h = hs; l = f2bf(x - bf2f(hs));
}

// ---- ONE prep kernel, task-split: KF(fp16) | VF(bf16) | mask bits ----
// K/V conversion traffic (~83MB) hides inside the 537MB mask stream's shadow.
__global__ __launch_bounds__(256) void prep_all(
    const float* __restrict__ K, const float* __restrict__ V,
    const int* __restrict__ M,
    unsigned short* __restrict__ KF, unsigned short* __restrict__ VF,
    unsigned long long* __restrict__ MW)
{
    __shared__ float Ts[64][65];
    const int bid = blockIdx.x;
    const int t = threadIdx.x;

    if (bid < 2048) {
        // ---- K -> fragment-interleaved fp16 ----
        const int bh = bid >> 4, kt = bid & 15;
        const int w = t >> 6, lane = t & 63;
        const int fr = lane & 15, g = lane >> 4;
        const float* src = K + (((size_t)(bh << 10) + (kt << 6) + (w << 4) + fr) << 6);
        const v4f a0 = __builtin_nontemporal_load((const v4f*)(src + (g << 3)));
        const v4f a1 = __builtin_nontemporal_load((const v4f*)(src + (g << 3) + 4));
        const v4f b0 = __builtin_nontemporal_load((const v4f*)(src + 32 + (g << 3)));
        const v4f b1 = __builtin_nontemporal_load((const v4f*)(src + 32 + (g << 3) + 4));
        v8h c0, c1;
        #pragma unroll
        for (int j = 0; j < 4; ++j) {
            c0[j] = (_Float16)a0[j]; c0[4 + j] = (_Float16)a1[j];
            c1[j] = (_Float16)b0[j]; c1[4 + j] = (_Float16)b1[j];
        }
        unsigned short* dst = KF + ((size_t)bh << 16) + ((size_t)((kt << 2) + w) << 10) + (lane << 3);
        *(v8h*)(dst)       = c0;
        *(v8h*)(dst + 512) = c1;
    } else if (bid < 4096) {
        // ---- V -> fragment-interleaved V^T bf16 ----
        const int b2 = bid - 2048;
        const int bh = b2 >> 4, kt = b2 & 15;
        {
            const int r = t >> 2, cs = (t & 3) << 4;
            const float* src = V + ((size_t)bh * Sn + (kt << 6) + r) * Dn + cs;
            const v4f a = __builtin_nontemporal_load((const v4f*)src);
            const v4f b = __builtin_nontemporal_load((const v4f*)src + 1);
            const v4f c = __builtin_nontemporal_load((const v4f*)src + 2);
            const v4f d = __builtin_nontemporal_load((const v4f*)src + 3);
            #pragma unroll
            for (int j = 0; j < 4; ++j) {
                Ts[r][cs + j]      = a[j];
                Ts[r][cs + 4 + j]  = b[j];
                Ts[r][cs + 8 + j]  = c[j];
                Ts[r][cs + 12 + j] = d[j];
            }
        }
        __syncthreads();
        {
            const int w = t >> 6, lane = t & 63;
            const int fr = lane & 15, g = lane >> 4;
            const int d = (w << 4) + fr;
            unsigned short* dst = VF + ((size_t)bh << 16) + ((size_t)((kt << 2) + w) << 10) + (lane << 3);
            v8u o0, o1;
            #pragma unroll
            for (int j = 0; j < 8; ++j) o0[j] = f2bf(Ts[(g << 3) + j][d]);
            #pragma unroll
            for (int j = 0; j < 8; ++j) o1[j] = f2bf(Ts[32 + (g << 3) + j][d]);
            *(v8u*)dst         = o0;
            *(v8u*)(dst + 512) = o1;
        }
    } else {
        // ---- mask int32 -> bit-packed u64 words (grid-stride) ----
        const int NW = 2097152;   // 128*1024*1024 / 64
        const int lane = t & 63;
        const int wave = ((bid - 4096) << 2) + (t >> 6);
        const int nwaves = 2048 << 2;
        for (int w0 = wave << 3; w0 < NW; w0 += nwaves << 3) {
            unsigned long long b[8];
            #pragma unroll
            for (int s = 0; s < 8; ++s) {
                const int v = __builtin_nontemporal_load(&M[((size_t)(w0 + s) << 6) + lane]);
                b[s] = __ballot(v != 0);
            }
            if (lane == 0) {
                ulonglong2* dst = (ulonglong2*)(MW + w0);
                ulonglong2 p0, p1, p2, p3;
                p0.x = b[0]; p0.y = b[1]; p1.x = b[2]; p1.y = b[3];
                p2.x = b[4]; p2.y = b[5]; p3.x = b[6]; p3.y = b[7];
                dst[0] = p0; dst[1] = p1; dst[2] = p2; dst[3] = p3;
            }
        }
    }
}

// ---- fused attention: fp16 QK^T; phase B BEFORE attn write (clean vm queue) ----
// Block: 16 q-rows, 4 waves, 4 blocks/CU (LDS = Ph only, 33 KB). Barrier-free
// phases; every fragment = one coalesced 1KB L2 load; depth-4 prefetch.
// Store bursts issue only AFTER all compute loads (in-order vmcnt discipline).
__global__ __launch_bounds__(256, 4) void fused_attn_f(
    const unsigned short* __restrict__ KFG, const unsigned short* __restrict__ VFG,
    const float* __restrict__ Q, const unsigned long long* __restrict__ MW,
    float* __restrict__ attnO, float* __restrict__ ctxO)
{
    __shared__ unsigned short Ph[16][PH_LD];
    __shared__ float rsumW[4][16];
    __shared__ float invL[16];

    const int tid  = threadIdx.x;
    const int lane = tid & 63;
    const int w    = tid >> 6;
    const int fr   = lane & 15;
    const int g    = lane >> 4;

    // bijective XCD swizzle: all 64 q-blocks of one bh on one XCD
    const int swz = ((blockIdx.x & 7) << 10) + (blockIdx.x >> 3);
    const int bh = swz >> 6;
    const int q0 = (swz & 63) << 4;

    const float* Qb = Q + (size_t)bh * Sn * Dn + (size_t)q0 * Dn;
    float*       Ab = attnO + (size_t)bh * Sn * Sn + (size_t)q0 * Sn;
    float*       Cb = ctxO  + (size_t)bh * Sn * Dn + (size_t)q0 * Dn;
    const unsigned short* KFb = KFG + ((size_t)bh << 16);
    const unsigned short* VFb = VFG + ((size_t)bh << 16);
    const unsigned long long* mwp = MW + ((size_t)bh << 14) + ((size_t)(q0 + fr) << 4);

    // Q B-fragments, fp16 (once per block)
    v8h qf0, qf1;
    {
        const float* qp = Qb + fr * Dn + (g << 3);
        const v4f x0a = *(const v4f*)qp;
        const v4f x0b = *(const v4f*)(qp + 4);
        const v4f x1a = *(const v4f*)(qp + 32);
        const v4f x1b = *(const v4f*)(qp + 36);
        #pragma unroll
        for (int j = 0; j < 4; ++j) {
            qf0[j] = (_Float16)x0a[j]; qf0[4 + j] = (_Float16)x0b[j];
            qf1[j] = (_Float16)x1a[j]; qf1[4 + j] = (_Float16)x1b[j];
        }
    }

    const int sh = (w << 4) + (g << 2);

#define LDK(kt, k0_, k1_) do {                                                     \
        const unsigned short* _p = KFb + ((size_t)(((kt) << 2) + w) << 10) + (lane << 3); \
        k0_ = *(const v8h*)_p;  k1_ = *(const v8h*)(_p + 512);                     \
    } while (0)

#define STEPA(k0_, k1_, mwv, kt) do {                                              \
        v4f acc = {0.f, 0.f, 0.f, 0.f};                                            \
        __builtin_amdgcn_s_setprio(1);                                             \
        acc = __builtin_amdgcn_mfma_f32_16x16x32_f16(k0_, qf0, acc, 0, 0, 0);      \
        acc = __builtin_amdgcn_mfma_f32_16x16x32_f16(k1_, qf1, acc, 0, 0, 0);      \
        __builtin_amdgcn_s_setprio(0);                                             \
        const unsigned mb = (unsigned)((mwv) >> sh);                               \
        const float e0 = (mb & 1u) ? 1.0f : __expf(acc[0]);                        \
        const float e1 = (mb & 2u) ? 1.0f : __expf(acc[1]);                        \
        const float e2 = (mb & 4u) ? 1.0f : __expf(acc[2]);                        \
        const float e3 = (mb & 8u) ? 1.0f : __expf(acc[3]);                        \
        rs += (e0 + e1) + (e2 + e3);                                               \
        ushort4 pk;                                                                \
        pk.x = f2bf(e0); pk.y = f2bf(e1); pk.z = f2bf(e2); pk.w = f2bf(e3);        \
        *(ushort4*)&Ph[fr][((kt) << 6) + (w << 4) + (g << 2)] = pk;                \
    } while (0)

    float rs = 0.f;

    // ---- Phase A: barrier-free; depth-4 K slots + depth-4 mask ring ----
    {
        v8h k0s[4], k1s[4];
        unsigned long long mk[4];
        LDK(0, k0s[0], k1s[0]);
        LDK(1, k0s[1], k1s[1]);
        LDK(2, k0s[2], k1s[2]);
        LDK(3, k0s[3], k1s[3]);
        mk[0] = mwp[0]; mk[1] = mwp[1]; mk[2] = mwp[2]; mk[3] = mwp[3];
        #pragma unroll
        for (int kt = 0; kt < 16; ++kt) {
            STEPA(k0s[kt & 3], k1s[kt & 3], mk[kt & 3], kt);
            if (kt + 4 < 16) {
                LDK(kt + 4, k0s[kt & 3], k1s[kt & 3]);
                mk[kt & 3] = mwp[kt + 4];
            }
        }
    }

    // ---- row-sum reduce (only barriers; raw, no vmcnt drain) ----
    rs += __shfl_xor(rs, 16);
    rs += __shfl_xor(rs, 32);
    if (g == 0) rsumW[w][fr] = rs;
    __builtin_amdgcn_sched_barrier(0);
    LGKM0();
    SBAR();
    if (tid < 16) {
        const float s = rsumW[0][tid] + rsumW[1][tid] + rsumW[2][tid] + rsumW[3][tid];
        invL[tid] = 1.0f / s;
    }
    __builtin_amdgcn_sched_barrier(0);
    LGKM0();
    SBAR();

#define LDV(kt, v0_, v1_) do {                                                     \
        const unsigned short* _p = VFb + ((size_t)(((kt) << 2) + w) << 10) + (lane << 3); \
        v0_ = *(const v8s*)_p;  v1_ = *(const v8s*)(_p + 512);                     \
    } while (0)

#define STEPB(v0_, v1_, kt) do {                                                   \
        const v8s a0 = *(const v8s*)&Ph[fr][((kt) << 6) + (g << 3)];               \
        const v8s a1 = *(const v8s*)&Ph[fr][((kt) << 6) + 32 + (g << 3)];          \
        __builtin_amdgcn_s_setprio(1);                                             \
        accp = __builtin_amdgcn_mfma_f32_16x16x32_bf16(a0, v0_, accp, 0, 0, 0);    \
        accp = __builtin_amdgcn_mfma_f32_16x16x32_bf16(a1, v1_, accp, 0, 0, 0);    \
        __builtin_amdgcn_s_setprio(0);                                             \
    } while (0)

    // ---- Phase B FIRST: load queue contains only loads (no store blocking) ----
    const int dcol = (w << 4) + fr;
    v4f accp = {0.f, 0.f, 0.f, 0.f};
    {
        v8s v0s[4], v1s[4];
        LDV(0, v0s[0], v1s[0]);
        LDV(1, v0s[1], v1s[1]);
        LDV(2, v0s[2], v1s[2]);
        LDV(3, v0s[3], v1s[3]);
        #pragma unroll
        for (int kt = 0; kt < 16; ++kt) {
            STEPB(v0s[kt & 3], v1s[kt & 3], kt);
            if (kt + 4 < 16) LDV(kt + 4, v0s[kt & 3], v1s[kt & 3]);
        }
    }
    #pragma unroll
    for (int r = 0; r < 4; ++r) {
        const int q = (g << 2) + r;
        __builtin_nontemporal_store(accp[r] * invL[q], &Cb[(size_t)q * Dn + dcol]);
    }

    // ---- attn write LAST (drain overlaps other blocks' compute) ----
    {
        const int qq = tid >> 4, ii = tid & 15;
        const float inv = invL[qq];
        float* arow = Ab + (size_t)qq * Sn;
        #pragma unroll
        for (int c = 0; c < 16; ++c) {
            const int k0 = (c << 6) + (ii << 2);
            const ushort4 p = *(const ushort4*)&Ph[qq][k0];
            v4f o;
            o[0] = bf2f(p.x) * inv; o[1] = bf2f(p.y) * inv;
            o[2] = bf2f(p.z) * inv; o[3] = bf2f(p.w) * inv;
            __builtin_nontemporal_store(o, (v4f*)(arow + k0));
        }
    }
#undef LDK
#undef STEPA
#undef LDV
#undef STEPB
}

// ---------------- fallback (round-3 kernel, in-kernel split) ----------------
__global__ __launch_bounds__(256, 3) void fused_attn_fb(
    const float* __restrict__ Q, const float* __restrict__ K,
    const float* __restrict__ V, const int* __restrict__ M,
    float* __restrict__ attnO, float* __restrict__ ctxO)
{
    __shared__ unsigned short Ph[16][1048];
    __shared__ __align__(16) unsigned short Kraw[2 * 64 * K_LD];
    __shared__ float rsumW[4][16];
    __shared__ float invL[16];

    unsigned short (*Khi)[K_LD] = (unsigned short (*)[K_LD])Kraw;
    unsigned short (*Klo)[K_LD] = (unsigned short (*)[K_LD])(Kraw + 64 * K_LD);
    unsigned short (*Vt)[V_LD]  = (unsigned short (*)[V_LD])Kraw;

    const int tid  = threadIdx.x;
    const int lane = tid & 63;
    const int w    = tid >> 6;
    const int fr   = lane & 15;
    const int g    = lane >> 4;

    const int bh = blockIdx.x >> 6;
    const int q0 = (blockIdx.x & 63) << 4;

    const float* Qb = Q + (size_t)bh * Sn * Dn + (size_t)q0 * Dn;
    const float* Kb = K + (size_t)bh * Sn * Dn;
    const float* Vb = V + (size_t)bh * Sn * Dn;
    const int*   Mb = M + (size_t)bh * Sn * Sn + (size_t)q0 * Sn;
    float*       Ab = attnO + (size_t)bh * Sn * Sn + (size_t)q0 * Sn;
    float*       Cb = ctxO  + (size_t)bh * Sn * Dn + (size_t)q0 * Dn;

    v8s qh0, qh1, ql0, ql1;
    {
        const float* qp = Qb + fr * Dn + (g << 3);
        float x0[8], x1[8];
        *(v4f*)&x0[0] = *(const v4f*)qp;
        *(v4f*)&x0[4] = *(const v4f*)(qp + 4);
        *(v4f*)&x1[0] = *(const v4f*)(qp + 32);
        *(v4f*)&x1[4] = *(const v4f*)(qp + 36);
        #pragma unroll
        for (int i = 0; i < 8; ++i) {
            unsigned short hh, ll;
            split2(x0[i], hh, ll); qh0[i] = (short)hh; ql0[i] = (short)ll;
            split2(x1[i], hh, ll); qh1[i] = (short)hh; ql1[i] = (short)ll;
        }
    }

    const int srow = tid >> 4;
    const int sc4  = (tid & 15) << 2;

    const int* mp = Mb + (size_t)fr * Sn + (w << 4) + (g << 2);
    v4i mv = *(const v4i*)mp;

    v4f ka[4];
    #pragma unroll
    for (int i = 0; i < 4; ++i)
        ka[i] = *(const v4f*)(Kb + (size_t)(srow + (i << 4)) * Dn + sc4);

    float rs = 0.f;

    for (int kt = 0; kt < 16; ++kt) {
        __syncthreads();
        v4f kb[4];
        if (kt < 15) {
            const float* kn = Kb + (size_t)((kt + 1) << 6) * Dn;
            #pragma unroll
            for (int i = 0; i < 4; ++i)
                kb[i] = *(const v4f*)(kn + (size_t)(srow + (i << 4)) * Dn + sc4);
        }
        v4i mnext = mv;
        if (kt < 15) mnext = *(const v4i*)(mp + ((kt + 1) << 6));

        #pragma unroll
        for (int i = 0; i < 4; ++i) {
            const int row = srow + (i << 4);
            ushort4 hv, lv;
            split2(ka[i][0], hv.x, lv.x); split2(ka[i][1], hv.y, lv.y);
            split2(ka[i][2], hv.z, lv.z); split2(ka[i][3], hv.w, lv.w);
            *(ushort4*)&Khi[row][sc4] = hv;
            *(ushort4*)&Klo[row][sc4] = lv;
        }
        __syncthreads();

        const int krow = (w << 4) + fr;
        const v8s kh0 = *(const v8s*)&Khi[krow][(g << 3)];
        const v8s kh1 = *(const v8s*)&Khi[krow][32 + (g << 3)];
        const v8s kl0 = *(const v8s*)&Klo[krow][(g << 3)];
        const v8s kl1 = *(const v8s*)&Klo[krow][32 + (g << 3)];

        v4f acc = {0.f, 0.f, 0.f, 0.f};
        acc = __builtin_amdgcn_mfma_f32_16x16x32_bf16(kh0, qh0, acc, 0, 0, 0);
        acc = __builtin_amdgcn_mfma_f32_16x16x32_bf16(kh1, qh1, acc, 0, 0, 0);
        acc = __builtin_amdgcn_mfma_f32_16x16x32_bf16(kl0, qh0, acc, 0, 0, 0);
        acc = __builtin_amdgcn_mfma_f32_16x16x32_bf16(kl1, qh1, acc, 0, 0, 0);
        acc = __builtin_amdgcn_mfma_f32_16x16x32_bf16(kh0, ql0, acc, 0, 0, 0);
        acc = __builtin_amdgcn_mfma_f32_16x16x32_bf16(kh1, ql1, acc, 0, 0, 0);

        const float e0 = mv[0] ? 1.0f : __expf(acc[0]);
        const float e1 = mv[1] ? 1.0f : __expf(acc[1]);
        const float e2 = mv[2] ? 1.0f : __expf(acc[2]);
        const float e3 = mv[3] ? 1.0f : __expf(acc[3]);
        rs += (e0 + e1) + (e2 + e3);
        ushort4 pk;
        pk.x = f2bf(e0); pk.y = f2bf(e1); pk.z = f2bf(e2); pk.w = f2bf(e3);
        *(ushort4*)&Ph[fr][(kt << 6) + (w << 4) + (g << 2)] = pk;

        mv = mnext;
        #pragma unroll
        for (int i = 0; i < 4; ++i) ka[i] = kb[i];
    }

    rs += __shfl_xor(rs, 16);
    rs += __shfl_xor(rs, 32);
    if (g == 0) rsumW[w][fr] = rs;
    __syncthreads();
    if (tid < 16) {
        const float s = rsumW[0][tid] + rsumW[1][tid] + rsumW[2][tid] + rsumW[3][tid];
        invL[tid] = 1.0f / s;
    }
    __syncthreads();

    const int dcol = (w << 4) + fr;
    v4f va[4];
    #pragma unroll
    for (int i = 0; i < 4; ++i)
        va[i] = *(const v4f*)(Vb + (size_t)(srow + (i << 4)) * Dn + sc4);

    v4f accp = {0.f, 0.f, 0.f, 0.f};
    for (int kt = 0; kt < 16; ++kt) {
        __syncthreads();
        v4f vb[4];
        if (kt < 15) {
            const float* vn = Vb + (size_t)((kt + 1) << 6) * Dn;
            #pragma unroll
            for (int i = 0; i < 4; ++i)
                vb[i] = *(const v4f*)(vn + (size_t)(srow + (i << 4)) * Dn + sc4);
        }
        #pragma unroll
        for (int i = 0; i < 4; ++i) {
            const int row = srow + (i << 4);
            Vt[sc4 + 0][row] = f2bf(va[i][0]);
            Vt[sc4 + 1][row] = f2bf(va[i][1]);
            Vt[sc4 + 2][row] = f2bf(va[i][2]);
            Vt[sc4 + 3][row] = f2bf(va[i][3]);
        }
        __syncthreads();

        #pragma unroll
        for (int c = 0; c < 2; ++c) {
            const int kc = (kt << 6) + (c << 5);
            const v8s a = *(const v8s*)&Ph[fr][kc + (g << 3)];
            const v8s b = *(const v8s*)&Vt[dcol][(c << 5) + (g << 3)];
            accp = __builtin_amdgcn_mfma_f32_16x16x32_bf16(a, b, accp, 0, 0, 0);
        }
        #pragma unroll
        for (int i = 0; i < 4; ++i) va[i] = vb[i];
    }
    #pragma unroll
    for (int r = 0; r < 4; ++r) {
        const int q = (g << 2) + r;
        Cb[(size_t)q * Dn + dcol] = accp[r] * invL[q];
    }

    {
        const int qq = tid >> 4, ii = tid & 15;
        const float inv = invL[qq];
        float* arow = Ab + (size_t)qq * Sn;
        #pragma unroll
        for (int c = 0; c < 16; ++c) {
            const int k0 = (c << 6) + (ii << 2);
            const ushort4 p = *(const ushort4*)&Ph[qq][k0];
            v4f o;
            o[0] = bf2f(p.x) * inv; o[1] = bf2f(p.y) * inv;
            o[2] = bf2f(p.z) * inv; o[3] = bf2f(p.w) * inv;
            *(v4f*)(arow + k0) = o;
        }
    }
}

extern "C" void kernel_launch(void* const* d_in, const int* in_sizes, int n_in,
                              void* d_out, int out_size, void* d_ws, size_t ws_size,
                              hipStream_t stream) {
    const float* Q    = (const float*)d_in[0];
    const float* K    = (const float*)d_in[1];
    const float* V    = (const float*)d_in[2];
    const int*   mask = (const int*)d_in[3];

    float* ctx  = (float*)d_out;                           // (B,H,S,D)
    float* attn = (float*)d_out + (size_t)128 * Sn * Dn;   // (B,H,S,S)

    const size_t NELEM = (size_t)128 * Sn * Dn;            // 8,388,608
    const size_t MWORDS = (size_t)128 * Sn * 16;           // 2,097,152 u64
    const size_t NEED  = NELEM * 4 + MWORDS * 8;           // KF 16.8 + VF 16.8 + bits 16.8 MB

    if (ws_size >= NEED) {
        unsigned short* KF = (unsigned short*)d_ws;        // fp16 frag-interleaved
        unsigned short* VF = KF + NELEM;                   // V^T bf16 frag-interleaved
        unsigned long long* MWp = (unsigned long long*)((char*)d_ws + NELEM * 4);
        prep_all<<<6144, 256, 0, stream>>>(K, V, mask, KF, VF, MWp);
        fused_attn_f<<<128 * 64, 256, 0, stream>>>(KF, VF, Q, MWp, attn, ctx);
    } else {
        fused_attn_fb<<<128 * 64, 256, 0, stream>>>(Q, K, V, mask, attn, ctx);
    }
}